// Round 4
// baseline (118.404 us; speedup 1.0000x reference)
//
#include <hip/hip_runtime.h>
#include <hip/hip_bf16.h>

#define NN_ 1024

// ws layout (~15 MB of 256 MiB ws)
#define U_WGF  0         // ushort idx: 131072  Wg fragment-major, quadrant-remapped:
                         //   ((jt*8+kb)*4+q)*128 + jl*8 + r ; jorig = (jt&3)*128+(jt>>2)*16+jl
#define U_SHI  131072    // ushort: 524288 W_soc bf16 hi, fragment-major ((g*4+j)*4+q)*512+e*8+r
#define U_ACTH 655360    // ushort: 262144 act_hi[n][k] 1024x256 (0-63 emb, 64-127 pool, 128-255 h0)
#define U_P    917504    // ushort: 4194304 P[m][g*64+e] bf16 (8 MB)
#define F_WOUT 2555904   // float idx: 16384 f32 WoutT[r][j] 128x128, j>=120 zero
#define F_HN   2572288   // float idx: 131072 f32 hn[n][r]
#define I_OFF  2703360   // uint idx: 1048576 per-agent neighbor offsets (1024 each)
#define I_CNT  3751936   // uint idx: 1024 per-agent neighbor counts

typedef __attribute__((ext_vector_type(8))) short short8;
typedef __attribute__((ext_vector_type(4))) float floatx4;

__device__ __forceinline__ float b2f_(unsigned short u) {
    return __uint_as_float(((unsigned)u) << 16);           // bf16 -> f32, exact
}
__device__ __forceinline__ unsigned short f2bu(float f) {  // f32 -> bf16 bits (RNE)
    __hip_bfloat16 b = __float2bfloat16(f);
    return *(unsigned short*)&b;
}
__device__ __forceinline__ float ldin(const void* p, int i, int isbf) {
    return isbf ? b2f_(((const unsigned short*)p)[i]) : ((const float*)p)[i];
}
__device__ __forceinline__ int detect_bf16(const void* Wih, int tid) {
    unsigned wv = ((const unsigned*)Wih)[tid];
    unsigned e8 = (wv >> 7) & 0xFFu;
    return (__syncthreads_count((e8 >= 96u && e8 <= 134u) ? 1 : 0) > 128) ? 1 : 0;
}

// ---- K0: minimal prep — only what pgemm consumes (SHI + ACTH-h). 320 blocks ----
__global__ __launch_bounds__(256) void prep_kernel(
        const void* __restrict__ h0,  const void* __restrict__ Wsoc,
        const void* __restrict__ Wih, float* __restrict__ ws) {
    const int tid = threadIdx.x;
    const int isbf = detect_bf16(Wih, tid);
    unsigned short* u = (unsigned short*)ws;
    const int t0 = 147456 + (blockIdx.x * 256 + tid) * 8;
    unsigned short hv[8];
    if (t0 < 671744) {                             // W_soc hi, fragment-major
        int t2 = t0 - 147456;
        int e = (t2 >> 3) & 63, q = (t2 >> 9) & 3, j = (t2 >> 11) & 3, g = t2 >> 13;
        int src = e * 8192 + g * 128 + j * 32 + q * 8;
#pragma unroll
        for (int r = 0; r < 8; r++) hv[r] = f2bu(ldin(Wsoc, src + r, isbf));
        *(short8*)(u + U_SHI + t2) = *(short8*)hv;
    } else {                                       // h0 -> act k=128..255
        int t2 = t0 - 671744; int n = t2 >> 7, k = t2 & 127;
#pragma unroll
        for (int i = 0; i < 8; i++) hv[i] = f2bu(ldin(h0, t2 + i, isbf));
        *(short8*)(u + U_ACTH + n * 256 + 128 + k) = *(short8*)hv;
    }
}

// ---- K1: P = h0 @ W_socT MFMA (2048 blocks, verbatim) + neighbor detect (256) ----
__global__ __launch_bounds__(256) void pgemm_kernel(const void* __restrict__ xabs,
                                                    const void* __restrict__ Wih_det,
                                                    float* __restrict__ ws) {
    const int tid = threadIdx.x;
    const int bid = blockIdx.x;
    const int isbf = detect_bf16(Wih_det, tid);
    const unsigned short* u = (const unsigned short*)ws;

    if (bid < 2048) {
        const short* Ah  = (const short*)(u + U_ACTH);
        const short* Shi = (const short*)(u + U_SHI);
        unsigned short* P16 = (unsigned short*)ws + U_P;
        const int lane = tid & 63, wv = tid >> 6;
        const int mtile = bid & 63, rest = bid >> 6;
        const int cg = rest >> 1, thalf = rest & 1;
        const int m = lane & 15, q = lane >> 4;
        const int g = cg * 4 + wv;                 // wave-uniform B row-group
        const int abase = (mtile * 16 + m) * 256 + 128 + q * 8;
        short8 ah[4];
#pragma unroll
        for (int j = 0; j < 4; j++) ah[j] = *(const short8*)(Ah + abase + 32 * j);
        const int rowl = mtile * 16 + q * 4;
#pragma unroll
        for (int tt = 0; tt < 2; tt++) {
            const int t = thalf * 2 + tt;
            const int e = t * 16 + m;
            floatx4 c = {0.0f, 0.0f, 0.0f, 0.0f};
#pragma unroll
            for (int j = 0; j < 4; j++) {
                short8 bh = *(const short8*)(Shi + ((g * 4 + j) * 4 + q) * 512 + e * 8);
                c = __builtin_amdgcn_mfma_f32_16x16x32_bf16(ah[j], bh, c, 0, 0, 0);
            }
            const int n0 = cg * 256 + wv * 64 + t * 16;
#pragma unroll
            for (int r = 0; r < 4; r++)            // D: col=lane&15, row=q*4+r
                P16[(rowl + r) * 4096 + n0 + m] = f2bu(c[r]);
        }
    } else {
        // neighbor detection, 4 agents/block -> OFF lists + CNT
        __shared__ float xs_[2048];
        __shared__ int cnt_s[4];
        for (int i = tid; i < 2048; i += 256) xs_[i] = ldin(xabs, i, isbf);
        if (tid < 4) cnt_s[tid] = 0;
        __syncthreads();
        const int a = tid >> 6, t = tid & 63;
        const int n = (bid - 2048) * 4 + a;
        unsigned* OFF = (unsigned*)ws + I_OFF + n * 1024;
        const float xsn = xs_[2 * n]     - 0.2f;   // x[n] - NS/2
        const float ysn = xs_[2 * n + 1] - 0.2f;
        for (int i = t; i < NN_; i += 64) {
            float dx = xs_[2 * i]     - xsn;
            float dy = xs_[2 * i + 1] - ysn;
            int cx = (int)floorf(dx / 0.4f * 8.0f);
            int cy = (int)floorf(dy / 0.4f * 8.0f);
            bool valid = (dx >= 0.0f) && (dx < 0.4f) && (dy >= 0.0f) && (dy < 0.4f)
                      && (cx >= 0) && (cx < 8) && (cy >= 0) && (cy < 8) && (i != n);
            if (valid) {
                int pos = atomicAdd(&cnt_s[a], 1);
                OFF[pos] = (unsigned)(i * 4096 + ((cy * 8 + cx) << 6));
            }
        }
        __syncthreads();
        if (tid < 4) ((unsigned*)ws)[I_CNT + (bid - 2048) * 4 + tid] = (unsigned)cnt_s[tid];
    }
}

// ---- K2: pool gather (1024 blocks, 32 streams x 8 lanes, 4-deep unroll)
//          + late conversions riding the grid: WGF (64), WoutT (8), emb (32) ----
__global__ __launch_bounds__(256) void pool_kernel(
        const void* __restrict__ xoff, const void* __restrict__ Wemb,
        const void* __restrict__ bemb, const void* __restrict__ b_soc,
        const void* __restrict__ Wih,  const void* __restrict__ Whh,
        const void* __restrict__ Wout, float* __restrict__ ws) {
    __shared__ int off_s[1024];
    __shared__ float red[32][64];
    const int tid = threadIdx.x;
    const int isbf = detect_bf16(Wih, tid);
    const int bid = blockIdx.x;
    unsigned short* u = (unsigned short*)ws;

    if (bid < 1024) {                              // gather for agent n = bid
        const int n = bid;
        const int cc = (int)((const unsigned*)ws)[I_CNT + n];
        {
            const unsigned* lst = (const unsigned*)ws + I_OFF + n * 1024;
            for (int j = tid; j < cc; j += 256) off_s[j] = (int)lst[j];
        }
        __syncthreads();
        {   // 32 streams x 8 e8-lanes, 16B/lane, 4 loads in flight
            const unsigned short* P16 = (const unsigned short*)ws + U_P;
            const int strm = tid >> 3, l = tid & 7;
            float acc[8] = {0.f, 0.f, 0.f, 0.f, 0.f, 0.f, 0.f, 0.f};
            int j = strm;
            while (j + 96 < cc) {
                int o0 = off_s[j], o1 = off_s[j + 32], o2 = off_s[j + 64], o3 = off_s[j + 96];
                short8 v0 = *(const short8*)(P16 + o0 + l * 8);
                short8 v1 = *(const short8*)(P16 + o1 + l * 8);
                short8 v2 = *(const short8*)(P16 + o2 + l * 8);
                short8 v3 = *(const short8*)(P16 + o3 + l * 8);
#pragma unroll
                for (int i = 0; i < 8; i++)
                    acc[i] += b2f_((unsigned short)v0[i]) + b2f_((unsigned short)v1[i])
                            + b2f_((unsigned short)v2[i]) + b2f_((unsigned short)v3[i]);
                j += 128;
            }
            while (j < cc) {
                int o0 = off_s[j];
                short8 v0 = *(const short8*)(P16 + o0 + l * 8);
#pragma unroll
                for (int i = 0; i < 8; i++) acc[i] += b2f_((unsigned short)v0[i]);
                j += 32;
            }
#pragma unroll
            for (int i = 0; i < 8; i++) red[strm][l * 8 + i] = acc[i];
        }
        __syncthreads();
        if (tid < 64) {
            float s = 0.0f;
#pragma unroll
            for (int s32 = 0; s32 < 32; s32++) s += red[s32][tid];
            float v = fmaxf(s + ldin(b_soc, tid, isbf), 0.0f);
            u[U_ACTH + n * 256 + 64 + tid] = f2bu(v);
        }
    } else if (bid < 1088) {                       // Wg fragment-major, quadrant-remapped
        const int t0 = (bid - 1024) * 2048 + tid * 8;
        const int jl = (t0 >> 3) & 15, q = (t0 >> 7) & 3, kb = (t0 >> 9) & 7, jt = t0 >> 12;
        const int j = (jt & 3) * 128 + (jt >> 2) * 16 + jl;
        const int k0 = kb * 32 + q * 8;
        unsigned short hv[8];
#pragma unroll
        for (int r = 0; r < 8; r++) {
            int k = k0 + r;
            float v = (k < 128) ? ldin(Wih, j * 128 + k, isbf)
                                : ldin(Whh, j * 128 + (k - 128), isbf);
            hv[r] = f2bu(v);
        }
        *(short8*)(u + U_WGF + t0) = *(short8*)hv;
    } else if (bid < 1096) {                       // WoutT f32 [r][j]
        const int t2 = (bid - 1088) * 2048 + tid * 8;
        const int r = t2 >> 7, j0 = t2 & 127;
#pragma unroll
        for (int i = 0; i < 8; i++) {
            int j = j0 + i;
            ws[F_WOUT + t2 + i] = (j < 120) ? ldin(Wout, j * 128 + r, isbf) : 0.0f;
        }
    } else {                                       // emb -> act k=0..63
        const int t2 = (bid - 1096) * 2048 + tid * 8;
        const int n = t2 >> 6, e0 = t2 & 63;
        const float x0 = ldin(xoff, 2 * n, isbf), x1 = ldin(xoff, 2 * n + 1, isbf);
        unsigned short hv[8];
#pragma unroll
        for (int i = 0; i < 8; i++) {
            int e = e0 + i;
            float v = fmaf(x0, ldin(Wemb, 2 * e, isbf),
                      fmaf(x1, ldin(Wemb, 2 * e + 1, isbf), ldin(bemb, e, isbf)));
            hv[i] = f2bu(fmaxf(v, 0.0f));
        }
        *(short8*)(u + U_ACTH + n * 256 + e0) = *(short8*)hv;
    }
}

// ---- K3: gates (hi-only MFMA, quadrant-remapped Wg) + LSTM pointwise -> hn ----
// grid (64,8): block = 16 agents x r-range [16y,16y+16) with ALL 4 quadrants.
__global__ __launch_bounds__(256) void gates_kernel(const void* __restrict__ c0,
                                                    const void* __restrict__ b_ih,
                                                    const void* __restrict__ b_hh,
                                                    const void* __restrict__ Wih_det,
                                                    float* __restrict__ ws) {
    __shared__ float gl[16][68];                   // [agent][quad*16 + jl]
    const int tid = threadIdx.x;
    const int isbf = detect_bf16(Wih_det, tid);
    const unsigned short* u = (const unsigned short*)ws;
    const short* Ah = (const short*)(u + U_ACTH);
    const short* Wg = (const short*)(u + U_WGF);
    const int lane = tid & 63, wv = tid >> 6, m = lane & 15, q = lane >> 4;
    const int m0 = blockIdx.x * 16, y = blockIdx.y;
    const int jt = y * 4 + wv;                     // fragment-major tile id
    floatx4 acc = {0.0f, 0.0f, 0.0f, 0.0f};
#pragma unroll
    for (int kb = 0; kb < 8; kb++) {
        short8 ah = *(const short8*)(Ah + (m0 + m) * 256 + kb * 32 + q * 8);
        short8 b  = *(const short8*)(Wg + (jt * 8 + kb) * 512 + q * 128 + m * 8);
        acc = __builtin_amdgcn_mfma_f32_16x16x32_bf16(ah, b, acc, 0, 0, 0);
    }
    const int jorig = wv * 128 + y * 16 + m;       // quadrant wv, row y*16+m
    const float bias = ldin(b_ih, jorig, isbf) + ldin(b_hh, jorig, isbf);
#pragma unroll
    for (int r = 0; r < 4; r++)                    // D row = q*4+r = agent local
        gl[q * 4 + r][wv * 16 + m] = acc[r] + bias;
    __syncthreads();
    {
        const int a = tid >> 4, rl = tid & 15;     // 16 agents x 16 r
        const int n = m0 + a, rg = y * 16 + rl;
        float iv = gl[a][rl],      fv = gl[a][16 + rl];
        float gv = gl[a][32 + rl], ov = gl[a][48 + rl];
        float si = 1.0f / (1.0f + expf(-iv));
        float sf = 1.0f / (1.0f + expf(-fv));
        float so = 1.0f / (1.0f + expf(-ov));
        float cc = sf * ldin(c0, n * 128 + rg, isbf) + si * tanhf(gv);
        ws[F_HN + n * 128 + rg] = so * tanhf(cc);
    }
}

// ---- K4: output projection from hn (f32 WoutT). 512 blocks, 2 agents ----
__global__ __launch_bounds__(256) void pwout_kernel(const void* __restrict__ b_out,
                                                    const void* __restrict__ Wih_det,
                                                    const float* __restrict__ ws,
                                                    float* __restrict__ out) {
    __shared__ __align__(16) float hnl[2][128];
    const int tid = threadIdx.x;
    const int isbf = detect_bf16(Wih_det, tid);
    const int n0 = blockIdx.x * 2;
    const int half = tid >> 7, t2 = tid & 127;
    const int n = n0 + half;
    hnl[half][t2] = ws[F_HN + n * 128 + t2];
    __syncthreads();
    if (t2 < 120) {
        int j = t2;
        float acc = ldin(b_out, j, isbf);
        for (int r = 0; r < 128; r += 4) {
            float4 hq = *(const float4*)&hnl[half][r];
            acc = fmaf(hq.x, ws[F_WOUT + (r + 0) * 128 + j], acc);
            acc = fmaf(hq.y, ws[F_WOUT + (r + 1) * 128 + j], acc);
            acc = fmaf(hq.z, ws[F_WOUT + (r + 2) * 128 + j], acc);
            acc = fmaf(hq.w, ws[F_WOUT + (r + 3) * 128 + j], acc);
        }
        int ch = j / 20, wc = j - ch * 20;
        out[ch * 20480 + n * 20 + wc] = acc;       // f32, [6][1024][20]
    }
}

extern "C" void kernel_launch(void* const* d_in, const int* in_sizes, int n_in,
                              void* d_out, int out_size, void* d_ws, size_t ws_size,
                              hipStream_t stream) {
    const void* xoff  = d_in[0];
    const void* xabs  = d_in[1];
    const void* h0    = d_in[2];
    const void* c0    = d_in[3];
    const void* W_emb = d_in[4];
    const void* b_emb = d_in[5];
    const void* W_soc = d_in[6];
    const void* b_soc = d_in[7];
    const void* W_ih  = d_in[8];
    const void* W_hh  = d_in[9];
    const void* b_ih  = d_in[10];
    const void* b_hh  = d_in[11];
    const void* W_out = d_in[12];
    const void* b_out = d_in[13];
    float* ws = (float*)d_ws;
    float* out = (float*)d_out;

    prep_kernel<<<320, 256, 0, stream>>>(h0, W_soc, W_ih, ws);
    pgemm_kernel<<<2304, 256, 0, stream>>>(xabs, W_ih, ws);
    pool_kernel<<<1128, 256, 0, stream>>>(xoff, W_emb, b_emb, b_soc,
                                          W_ih, W_hh, W_out, ws);
    gates_kernel<<<dim3(64, 8), 256, 0, stream>>>(c0, b_ih, b_hh, W_ih, ws);
    pwout_kernel<<<512, 256, 0, stream>>>(b_out, W_ih, ws, out);
}

// Round 5
// 118.325 us; speedup vs baseline: 1.0007x; 1.0007x over previous
//
#include <hip/hip_runtime.h>
#include <hip/hip_cooperative_groups.h>
#include <hip/hip_bf16.h>

namespace cg = cooperative_groups;

#define NN_ 1024

// ws layout (~15 MB of 256 MiB ws) — identical to round 3
#define U_WGF  0         // ushort idx: 131072  Wg fragment-major, quadrant-remapped:
                         //   ((jt*8+kb)*4+q)*128 + jl*8 + r ; jorig = (jt&3)*128+(jt>>2)*16+jl
#define U_SHI  131072    // ushort: 524288 W_soc bf16 hi, fragment-major ((g*4+j)*4+q)*512+e*8+r
#define U_ACTH 655360    // ushort: 262144 act_hi[n][k] 1024x256 (0-63 emb, 64-127 pool, 128-255 h0)
#define U_P    917504    // ushort: 4194304 P[m][g*64+e] bf16 (8 MB)
#define F_WOUT 2555904   // float idx: 16384 f32 WoutT[r][j] 128x128, j>=120 zero
#define F_HN   2572288   // float idx: 131072 f32 hn[n][r]
#define I_OFF  2703360   // uint idx: 1048576 per-agent neighbor offsets (1024 each)
#define I_CNT  3751936   // uint idx: 1024 per-agent neighbor counts

typedef __attribute__((ext_vector_type(8))) short short8;
typedef __attribute__((ext_vector_type(4))) float floatx4;

__device__ __forceinline__ float b2f_(unsigned short u) {
    return __uint_as_float(((unsigned)u) << 16);           // bf16 -> f32, exact
}
__device__ __forceinline__ unsigned short f2bu(float f) {  // f32 -> bf16 bits (RNE)
    __hip_bfloat16 b = __float2bfloat16(f);
    return *(unsigned short*)&b;
}
__device__ __forceinline__ float ldin(const void* p, int i, int isbf) {
    return isbf ? b2f_(((const unsigned short*)p)[i]) : ((const float*)p)[i];
}
__device__ __forceinline__ int detect_bf16(const void* Wih, int tid) {
    unsigned wv = ((const unsigned*)Wih)[tid];
    unsigned e8 = (wv >> 7) & 0xFFu;
    return (__syncthreads_count((e8 >= 96u && e8 <= 134u) ? 1 : 0) > 128) ? 1 : 0;
}

// ============================================================================
// Cooperative mega-kernel: 1024 blocks x 256 threads, 4 blocks/CU co-resident.
// Phases = round-3 kernels verbatim, separated by grid.sync().
// ============================================================================
__global__ __launch_bounds__(256, 4) void mega_kernel(
        const void* __restrict__ xoff, const void* __restrict__ xabs,
        const void* __restrict__ h0,   const void* __restrict__ c0,
        const void* __restrict__ Wemb, const void* __restrict__ bemb,
        const void* __restrict__ Wsoc, const void* __restrict__ bsoc,
        const void* __restrict__ Wih,  const void* __restrict__ Whh,
        const void* __restrict__ bih,  const void* __restrict__ bhh,
        const void* __restrict__ Wout, const void* __restrict__ bout,
        float* __restrict__ ws,        float* __restrict__ out) {
    const int tid = threadIdx.x;
    const int bid = blockIdx.x;
    const int isbf = detect_bf16(Wih, tid);
    unsigned short* u = (unsigned short*)ws;
    __shared__ __align__(16) char smem[8704];
    cg::grid_group grid = cg::this_grid();

    // ---- Phase A: one-time conversions (424 block-units) + detect (256) ----
    if (bid < 424) {
        const int t0 = (bid * 256 + tid) * 8;
        unsigned short hv[8];
        if (t0 < 131072) {                         // Wg fragment-major, quadrant-remapped
            int jl = (t0 >> 3) & 15, q = (t0 >> 7) & 3, kb = (t0 >> 9) & 7, jt = t0 >> 12;
            int j = (jt & 3) * 128 + (jt >> 2) * 16 + jl;
            int k0 = kb * 32 + q * 8;
#pragma unroll
            for (int r = 0; r < 8; r++) {
                int k = k0 + r;
                float v = (k < 128) ? ldin(Wih, j * 128 + k, isbf)
                                    : ldin(Whh, j * 128 + (k - 128), isbf);
                hv[r] = f2bu(v);
            }
            *(short8*)(u + U_WGF + t0) = *(short8*)hv;
        } else if (t0 < 147456) {                  // WoutT f32 [r][j]
            int t2 = t0 - 131072; int r = t2 >> 7, j0 = t2 & 127;
#pragma unroll
            for (int i = 0; i < 8; i++) {
                int j = j0 + i;
                ws[F_WOUT + t2 + i] = (j < 120) ? ldin(Wout, j * 128 + r, isbf) : 0.0f;
            }
        } else if (t0 < 671744) {                  // W_soc hi, fragment-major
            int t2 = t0 - 147456;
            int e = (t2 >> 3) & 63, q = (t2 >> 9) & 3, j = (t2 >> 11) & 3, g = t2 >> 13;
            int src = e * 8192 + g * 128 + j * 32 + q * 8;
#pragma unroll
            for (int r = 0; r < 8; r++) hv[r] = f2bu(ldin(Wsoc, src + r, isbf));
            *(short8*)(u + U_SHI + t2) = *(short8*)hv;
        } else if (t0 < 802816) {                  // h0 -> act k=128..255
            int t2 = t0 - 671744; int n = t2 >> 7, k = t2 & 127;
#pragma unroll
            for (int i = 0; i < 8; i++) hv[i] = f2bu(ldin(h0, t2 + i, isbf));
            *(short8*)(u + U_ACTH + n * 256 + 128 + k) = *(short8*)hv;
        } else {                                   // emb -> act k=0..63
            int t2 = t0 - 802816; int n = t2 >> 6, e0 = t2 & 63;
            float x0 = ldin(xoff, 2 * n, isbf), x1 = ldin(xoff, 2 * n + 1, isbf);
#pragma unroll
            for (int i = 0; i < 8; i++) {
                int e = e0 + i;
                float v = fmaf(x0, ldin(Wemb, 2 * e, isbf),
                          fmaf(x1, ldin(Wemb, 2 * e + 1, isbf), ldin(bemb, e, isbf)));
                hv[i] = f2bu(fmaxf(v, 0.0f));
            }
            *(short8*)(u + U_ACTH + n * 256 + e0) = *(short8*)hv;
        }
    } else if (bid < 680) {
        // neighbor detection, 4 agents/block -> OFF lists + CNT
        float* xs_  = (float*)smem;                // 8192 B
        int*  cnt_s = (int*)(smem + 8192);         // 16 B
        for (int i = tid; i < 2048; i += 256) xs_[i] = ldin(xabs, i, isbf);
        if (tid < 4) cnt_s[tid] = 0;
        __syncthreads();
        const int a = tid >> 6, t = tid & 63;
        const int n = (bid - 424) * 4 + a;
        unsigned* OFF = (unsigned*)ws + I_OFF + n * 1024;
        const float xsn = xs_[2 * n]     - 0.2f;   // x[n] - NS/2
        const float ysn = xs_[2 * n + 1] - 0.2f;
        for (int i = t; i < NN_; i += 64) {
            float dx = xs_[2 * i]     - xsn;
            float dy = xs_[2 * i + 1] - ysn;
            int cx = (int)floorf(dx / 0.4f * 8.0f);
            int cy = (int)floorf(dy / 0.4f * 8.0f);
            bool valid = (dx >= 0.0f) && (dx < 0.4f) && (dy >= 0.0f) && (dy < 0.4f)
                      && (cx >= 0) && (cx < 8) && (cy >= 0) && (cy < 8) && (i != n);
            if (valid) {
                int pos = atomicAdd(&cnt_s[a], 1);
                OFF[pos] = (unsigned)(i * 4096 + ((cy * 8 + cx) << 6));
            }
        }
        __syncthreads();
        if (tid < 4) ((unsigned*)ws)[I_CNT + (bid - 424) * 4 + tid] = (unsigned)cnt_s[tid];
    }
    grid.sync();

    // ---- Phase B: P = h0 @ W_socT, hi-only MFMA. 2048 units, 2 per block ----
    {
        const short* Ah  = (const short*)(u + U_ACTH);
        const short* Shi = (const short*)(u + U_SHI);
        unsigned short* P16 = u + U_P;
        const int lane = tid & 63, wv = tid >> 6;
        const int m = lane & 15, q = lane >> 4;
#pragma unroll
        for (int u2 = 0; u2 < 2; ++u2) {
            const int B_ = bid * 2 + u2;           // 0..2047
            const int mtile = B_ & 63, rest = B_ >> 6;
            const int cgn = rest >> 1, thalf = rest & 1;
            const int g = cgn * 4 + wv;            // wave-uniform B row-group
            const int abase = (mtile * 16 + m) * 256 + 128 + q * 8;
            short8 ah[4];
#pragma unroll
            for (int j = 0; j < 4; j++) ah[j] = *(const short8*)(Ah + abase + 32 * j);
            const int rowl = mtile * 16 + q * 4;
#pragma unroll
            for (int tt = 0; tt < 2; tt++) {
                const int t = thalf * 2 + tt;
                const int e = t * 16 + m;
                floatx4 c = {0.0f, 0.0f, 0.0f, 0.0f};
#pragma unroll
                for (int j = 0; j < 4; j++) {
                    short8 bh = *(const short8*)(Shi + ((g * 4 + j) * 4 + q) * 512 + e * 8);
                    c = __builtin_amdgcn_mfma_f32_16x16x32_bf16(ah[j], bh, c, 0, 0, 0);
                }
                const int n0 = cgn * 256 + wv * 64 + t * 16;
#pragma unroll
                for (int r = 0; r < 4; r++)        // D: col=lane&15, row=q*4+r
                    P16[(rowl + r) * 4096 + n0 + m] = f2bu(c[r]);
            }
        }
    }
    grid.sync();

    // ---- Phase C: pool gather, agent n = bid (16 streams x 16 e4-lanes) ----
    {
        int*    off_s = (int*)smem;                         // 4096 B
        float4 (*red4)[16] = (float4(*)[16])(smem + 4096);  // 4096 B
        const int n = bid;
        const int cc = (int)((const unsigned*)ws)[I_CNT + n];
        {
            const unsigned* lst = (const unsigned*)ws + I_OFF + n * 1024;
            for (int j = tid; j < cc; j += 256) off_s[j] = (int)lst[j];
        }
        __syncthreads();
        {
            const unsigned short* P16 = (const unsigned short*)ws + U_P;
            const int strm = tid >> 4, e4 = tid & 15;
            float ax = 0.0f, ay = 0.0f, az = 0.0f, aw = 0.0f;
            for (int j = strm; j < cc; j += 16) {
                int o = off_s[j];
                ushort4 uu = *(const ushort4*)(P16 + o + 4 * e4);
                ax += b2f_(uu.x); ay += b2f_(uu.y); az += b2f_(uu.z); aw += b2f_(uu.w);
            }
            red4[strm][e4] = make_float4(ax, ay, az, aw);
        }
        __syncthreads();
        if (tid < 16) {
            float s[4] = {0.0f, 0.0f, 0.0f, 0.0f};
#pragma unroll
            for (int s16 = 0; s16 < 16; s16++) {
                float4 r = red4[s16][tid];
                s[0] += r.x; s[1] += r.y; s[2] += r.z; s[3] += r.w;
            }
            int e = 4 * tid;
#pragma unroll
            for (int i = 0; i < 4; i++) {
                float v = fmaxf(s[i] + ldin(bsoc, e + i, isbf), 0.0f);
                u[U_ACTH + n * 256 + 64 + e + i] = f2bu(v);
            }
        }
    }
    grid.sync();

    // ---- Phase D: gates MFMA + LSTM pointwise -> hn. 512 units ----
    if (bid < 512) {
        float (*gl)[68] = (float(*)[68])smem;      // 4352 B
        const short* Ah = (const short*)(u + U_ACTH);
        const short* Wg = (const short*)(u + U_WGF);
        const int lane = tid & 63, wv = tid >> 6, m = lane & 15, q = lane >> 4;
        const int m0 = (bid & 63) * 16, y = bid >> 6;
        const int jt = y * 4 + wv;                 // fragment-major tile id
        floatx4 acc = {0.0f, 0.0f, 0.0f, 0.0f};
#pragma unroll
        for (int kb = 0; kb < 8; kb++) {
            short8 ah = *(const short8*)(Ah + (m0 + m) * 256 + kb * 32 + q * 8);
            short8 b  = *(const short8*)(Wg + (jt * 8 + kb) * 512 + q * 128 + m * 8);
            acc = __builtin_amdgcn_mfma_f32_16x16x32_bf16(ah, b, acc, 0, 0, 0);
        }
        const int jorig = wv * 128 + y * 16 + m;   // quadrant wv, row y*16+m
        const float bias = ldin(bih, jorig, isbf) + ldin(bhh, jorig, isbf);
#pragma unroll
        for (int r = 0; r < 4; r++)                // D row = q*4+r = agent local
            gl[q * 4 + r][wv * 16 + m] = acc[r] + bias;
        __syncthreads();
        {
            const int a = tid >> 4, rl = tid & 15; // 16 agents x 16 r
            const int n = m0 + a, rg = y * 16 + rl;
            float iv = gl[a][rl],      fv = gl[a][16 + rl];
            float gv = gl[a][32 + rl], ov = gl[a][48 + rl];
            float si = 1.0f / (1.0f + expf(-iv));
            float sf = 1.0f / (1.0f + expf(-fv));
            float so = 1.0f / (1.0f + expf(-ov));
            float cc = sf * ldin(c0, n * 128 + rg, isbf) + si * tanhf(gv);
            ws[F_HN + n * 128 + rg] = so * tanhf(cc);
        }
    }
    grid.sync();

    // ---- Phase E: output projection from hn (f32 WoutT). 512 units, 2 agents ----
    if (bid < 512) {
        float (*hnl)[128] = (float(*)[128])smem;   // 1024 B
        const int n0 = bid * 2;
        const int half = tid >> 7, t2 = tid & 127;
        const int n = n0 + half;
        hnl[half][t2] = ws[F_HN + n * 128 + t2];
        __syncthreads();
        if (t2 < 120) {
            int j = t2;
            float acc = ldin(bout, j, isbf);
            for (int r = 0; r < 128; r += 4) {
                float4 hq = *(const float4*)&hnl[half][r];
                acc = fmaf(hq.x, ws[F_WOUT + (r + 0) * 128 + j], acc);
                acc = fmaf(hq.y, ws[F_WOUT + (r + 1) * 128 + j], acc);
                acc = fmaf(hq.z, ws[F_WOUT + (r + 2) * 128 + j], acc);
                acc = fmaf(hq.w, ws[F_WOUT + (r + 3) * 128 + j], acc);
            }
            int ch = j / 20, wc = j - ch * 20;
            out[ch * 20480 + n * 20 + wc] = acc;   // f32, [6][1024][20]
        }
    }
}

// ============================================================================
// Fallback path: round-3 five-kernel sequence (verbatim), used only if the
// cooperative launch cannot be honored on this device/runtime.
// ============================================================================
__global__ __launch_bounds__(256) void prep_kernel(
        const void* __restrict__ xoff, const void* __restrict__ xabs,
        const void* __restrict__ h0,
        const void* __restrict__ Wsoc, const void* __restrict__ Wemb,
        const void* __restrict__ bemb, const void* __restrict__ Wih,
        const void* __restrict__ Whh,  const void* __restrict__ Wout,
        float* __restrict__ ws) {
    const int tid = threadIdx.x;
    const int bid = blockIdx.x;
    const int isbf = detect_bf16(Wih, tid);
    unsigned short* u = (unsigned short*)ws;

    if (bid < 424) {
        const int t0 = (bid * 256 + tid) * 8;
        unsigned short hv[8];
        if (t0 < 131072) {
            int jl = (t0 >> 3) & 15, q = (t0 >> 7) & 3, kb = (t0 >> 9) & 7, jt = t0 >> 12;
            int j = (jt & 3) * 128 + (jt >> 2) * 16 + jl;
            int k0 = kb * 32 + q * 8;
#pragma unroll
            for (int r = 0; r < 8; r++) {
                int k = k0 + r;
                float v = (k < 128) ? ldin(Wih, j * 128 + k, isbf)
                                    : ldin(Whh, j * 128 + (k - 128), isbf);
                hv[r] = f2bu(v);
            }
            *(short8*)(u + U_WGF + t0) = *(short8*)hv;
        } else if (t0 < 147456) {
            int t2 = t0 - 131072; int r = t2 >> 7, j0 = t2 & 127;
#pragma unroll
            for (int i = 0; i < 8; i++) {
                int j = j0 + i;
                ws[F_WOUT + t2 + i] = (j < 120) ? ldin(Wout, j * 128 + r, isbf) : 0.0f;
            }
        } else if (t0 < 671744) {
            int t2 = t0 - 147456;
            int e = (t2 >> 3) & 63, q = (t2 >> 9) & 3, j = (t2 >> 11) & 3, g = t2 >> 13;
            int src = e * 8192 + g * 128 + j * 32 + q * 8;
#pragma unroll
            for (int r = 0; r < 8; r++) hv[r] = f2bu(ldin(Wsoc, src + r, isbf));
            *(short8*)(u + U_SHI + t2) = *(short8*)hv;
        } else if (t0 < 802816) {
            int t2 = t0 - 671744; int n = t2 >> 7, k = t2 & 127;
#pragma unroll
            for (int i = 0; i < 8; i++) hv[i] = f2bu(ldin(h0, t2 + i, isbf));
            *(short8*)(u + U_ACTH + n * 256 + 128 + k) = *(short8*)hv;
        } else {
            int t2 = t0 - 802816; int n = t2 >> 6, e0 = t2 & 63;
            float x0 = ldin(xoff, 2 * n, isbf), x1 = ldin(xoff, 2 * n + 1, isbf);
#pragma unroll
            for (int i = 0; i < 8; i++) {
                int e = e0 + i;
                float v = fmaf(x0, ldin(Wemb, 2 * e, isbf),
                          fmaf(x1, ldin(Wemb, 2 * e + 1, isbf), ldin(bemb, e, isbf)));
                hv[i] = f2bu(fmaxf(v, 0.0f));
            }
            *(short8*)(u + U_ACTH + n * 256 + e0) = *(short8*)hv;
        }
    } else {
        __shared__ float xs_[2048];
        __shared__ int cnt_s[4];
        for (int i = tid; i < 2048; i += 256) xs_[i] = ldin(xabs, i, isbf);
        if (tid < 4) cnt_s[tid] = 0;
        __syncthreads();
        const int a = tid >> 6, t = tid & 63;
        const int n = (bid - 424) * 4 + a;
        unsigned* OFF = (unsigned*)ws + I_OFF + n * 1024;
        const float xsn = xs_[2 * n]     - 0.2f;
        const float ysn = xs_[2 * n + 1] - 0.2f;
        for (int i = t; i < NN_; i += 64) {
            float dx = xs_[2 * i]     - xsn;
            float dy = xs_[2 * i + 1] - ysn;
            int cx = (int)floorf(dx / 0.4f * 8.0f);
            int cy = (int)floorf(dy / 0.4f * 8.0f);
            bool valid = (dx >= 0.0f) && (dx < 0.4f) && (dy >= 0.0f) && (dy < 0.4f)
                      && (cx >= 0) && (cx < 8) && (cy >= 0) && (cy < 8) && (i != n);
            if (valid) {
                int pos = atomicAdd(&cnt_s[a], 1);
                OFF[pos] = (unsigned)(i * 4096 + ((cy * 8 + cx) << 6));
            }
        }
        __syncthreads();
        if (tid < 4) ((unsigned*)ws)[I_CNT + (bid - 424) * 4 + tid] = (unsigned)cnt_s[tid];
    }
}

__global__ __launch_bounds__(256) void pgemm_kernel(float* __restrict__ ws) {
    const unsigned short* u = (const unsigned short*)ws;
    const short* Ah  = (const short*)(u + U_ACTH);
    const short* Shi = (const short*)(u + U_SHI);
    unsigned short* P16 = (unsigned short*)ws + U_P;
    const int tid = threadIdx.x, lane = tid & 63, wv = tid >> 6;
    const int B_ = blockIdx.y * 64 + blockIdx.x;
    const int mtile = B_ & 63, rest = B_ >> 6;
    const int cgn = rest >> 1, thalf = rest & 1;
    const int m = lane & 15, q = lane >> 4;
    const int g = cgn * 4 + wv;
    const int abase = (mtile * 16 + m) * 256 + 128 + q * 8;
    short8 ah[4];
#pragma unroll
    for (int j = 0; j < 4; j++) ah[j] = *(const short8*)(Ah + abase + 32 * j);
    const int rowl = mtile * 16 + q * 4;
#pragma unroll
    for (int tt = 0; tt < 2; tt++) {
        const int t = thalf * 2 + tt;
        const int e = t * 16 + m;
        floatx4 c = {0.0f, 0.0f, 0.0f, 0.0f};
#pragma unroll
        for (int j = 0; j < 4; j++) {
            short8 bh = *(const short8*)(Shi + ((g * 4 + j) * 4 + q) * 512 + e * 8);
            c = __builtin_amdgcn_mfma_f32_16x16x32_bf16(ah[j], bh, c, 0, 0, 0);
        }
        const int n0 = cgn * 256 + wv * 64 + t * 16;
#pragma unroll
        for (int r = 0; r < 4; r++)
            P16[(rowl + r) * 4096 + n0 + m] = f2bu(c[r]);
    }
}

__global__ __launch_bounds__(256) void pool_kernel(const void* __restrict__ b_soc,
                                                   const void* __restrict__ Wih_det,
                                                   float* __restrict__ ws) {
    __shared__ int off_s[1024];
    __shared__ float4 red4[16][16];
    const int tid = threadIdx.x;
    const int isbf = detect_bf16(Wih_det, tid);
    const int n = blockIdx.x;
    unsigned short* u = (unsigned short*)ws;
    const int cc = (int)((const unsigned*)ws)[I_CNT + n];
    {
        const unsigned* lst = (const unsigned*)ws + I_OFF + n * 1024;
        for (int j = tid; j < cc; j += 256) off_s[j] = (int)lst[j];
    }
    __syncthreads();
    {
        const unsigned short* P16 = (const unsigned short*)ws + U_P;
        const int strm = tid >> 4, e4 = tid & 15;
        float ax = 0.0f, ay = 0.0f, az = 0.0f, aw = 0.0f;
        for (int j = strm; j < cc; j += 16) {
            int o = off_s[j];
            ushort4 uu = *(const ushort4*)(P16 + o + 4 * e4);
            ax += b2f_(uu.x); ay += b2f_(uu.y); az += b2f_(uu.z); aw += b2f_(uu.w);
        }
        red4[strm][e4] = make_float4(ax, ay, az, aw);
    }
    __syncthreads();
    if (tid < 16) {
        float s[4] = {0.0f, 0.0f, 0.0f, 0.0f};
#pragma unroll
        for (int s16 = 0; s16 < 16; s16++) {
            float4 r = red4[s16][tid];
            s[0] += r.x; s[1] += r.y; s[2] += r.z; s[3] += r.w;
        }
        int e = 4 * tid;
#pragma unroll
        for (int i = 0; i < 4; i++) {
            float v = fmaxf(s[i] + ldin(b_soc, e + i, isbf), 0.0f);
            u[U_ACTH + n * 256 + 64 + e + i] = f2bu(v);
        }
    }
}

__global__ __launch_bounds__(256) void gates_kernel(const void* __restrict__ c0,
                                                    const void* __restrict__ b_ih,
                                                    const void* __restrict__ b_hh,
                                                    const void* __restrict__ Wih_det,
                                                    float* __restrict__ ws) {
    __shared__ float gl[16][68];
    const int tid = threadIdx.x;
    const int isbf = detect_bf16(Wih_det, tid);
    const unsigned short* u = (const unsigned short*)ws;
    const short* Ah = (const short*)(u + U_ACTH);
    const short* Wg = (const short*)(u + U_WGF);
    const int lane = tid & 63, wv = tid >> 6, m = lane & 15, q = lane >> 4;
    const int m0 = blockIdx.x * 16, y = blockIdx.y;
    const int jt = y * 4 + wv;
    floatx4 acc = {0.0f, 0.0f, 0.0f, 0.0f};
#pragma unroll
    for (int kb = 0; kb < 8; kb++) {
        short8 ah = *(const short8*)(Ah + (m0 + m) * 256 + kb * 32 + q * 8);
        short8 b  = *(const short8*)(Wg + (jt * 8 + kb) * 512 + q * 128 + m * 8);
        acc = __builtin_amdgcn_mfma_f32_16x16x32_bf16(ah, b, acc, 0, 0, 0);
    }
    const int jorig = wv * 128 + y * 16 + m;
    const float bias = ldin(b_ih, jorig, isbf) + ldin(b_hh, jorig, isbf);
#pragma unroll
    for (int r = 0; r < 4; r++)
        gl[q * 4 + r][wv * 16 + m] = acc[r] + bias;
    __syncthreads();
    {
        const int a = tid >> 4, rl = tid & 15;
        const int n = m0 + a, rg = y * 16 + rl;
        float iv = gl[a][rl],      fv = gl[a][16 + rl];
        float gv = gl[a][32 + rl], ov = gl[a][48 + rl];
        float si = 1.0f / (1.0f + expf(-iv));
        float sf = 1.0f / (1.0f + expf(-fv));
        float so = 1.0f / (1.0f + expf(-ov));
        float cc = sf * ldin(c0, n * 128 + rg, isbf) + si * tanhf(gv);
        ws[F_HN + n * 128 + rg] = so * tanhf(cc);
    }
}

__global__ __launch_bounds__(256) void pwout_kernel(const void* __restrict__ b_out,
                                                    const void* __restrict__ Wih_det,
                                                    const float* __restrict__ ws,
                                                    float* __restrict__ out) {
    __shared__ __align__(16) float hnl[2][128];
    const int tid = threadIdx.x;
    const int isbf = detect_bf16(Wih_det, tid);
    const int n0 = blockIdx.x * 2;
    const int half = tid >> 7, t2 = tid & 127;
    const int n = n0 + half;
    hnl[half][t2] = ws[F_HN + n * 128 + t2];
    __syncthreads();
    if (t2 < 120) {
        int j = t2;
        float acc = ldin(b_out, j, isbf);
        for (int r = 0; r < 128; r += 4) {
            float4 hq = *(const float4*)&hnl[half][r];
            acc = fmaf(hq.x, ws[F_WOUT + (r + 0) * 128 + j], acc);
            acc = fmaf(hq.y, ws[F_WOUT + (r + 1) * 128 + j], acc);
            acc = fmaf(hq.z, ws[F_WOUT + (r + 2) * 128 + j], acc);
            acc = fmaf(hq.w, ws[F_WOUT + (r + 3) * 128 + j], acc);
        }
        int ch = j / 20, wc = j - ch * 20;
        out[ch * 20480 + n * 20 + wc] = acc;
    }
}

extern "C" void kernel_launch(void* const* d_in, const int* in_sizes, int n_in,
                              void* d_out, int out_size, void* d_ws, size_t ws_size,
                              hipStream_t stream) {
    const void* xoff  = d_in[0];
    const void* xabs  = d_in[1];
    const void* h0    = d_in[2];
    const void* c0    = d_in[3];
    const void* W_emb = d_in[4];
    const void* b_emb = d_in[5];
    const void* W_soc = d_in[6];
    const void* b_soc = d_in[7];
    const void* W_ih  = d_in[8];
    const void* W_hh  = d_in[9];
    const void* b_ih  = d_in[10];
    const void* b_hh  = d_in[11];
    const void* W_out = d_in[12];
    const void* b_out = d_in[13];
    float* ws = (float*)d_ws;
    float* out = (float*)d_out;

    // One-time capability check: 1024 blocks must be co-resident (4 blocks/CU).
    static int use_coop = -1;
    if (use_coop < 0) {
        int nb = 0, ncu = 0, dev = 0, coop = 0;
        hipError_t e1 = hipOccupancyMaxActiveBlocksPerMultiprocessor(
                            &nb, (const void*)mega_kernel, 256, 0);
        hipGetDevice(&dev);
        hipError_t e2 = hipDeviceGetAttribute(&ncu, hipDeviceAttributeMultiprocessorCount, dev);
        hipError_t e3 = hipDeviceGetAttribute(&coop, hipDeviceAttributeCooperativeLaunch, dev);
        use_coop = (e1 == hipSuccess && e2 == hipSuccess && e3 == hipSuccess &&
                    coop != 0 && nb * ncu >= 1024) ? 1 : 0;
    }

    if (use_coop) {
        void* args[] = {(void*)&xoff, (void*)&xabs, (void*)&h0, (void*)&c0,
                        (void*)&W_emb, (void*)&b_emb, (void*)&W_soc, (void*)&b_soc,
                        (void*)&W_ih, (void*)&W_hh, (void*)&b_ih, (void*)&b_hh,
                        (void*)&W_out, (void*)&b_out, (void*)&ws, (void*)&out};
        hipError_t e = hipLaunchCooperativeKernel((const void*)mega_kernel,
                                                  dim3(1024), dim3(256),
                                                  args, 0, stream);
        if (e == hipSuccess) return;
        use_coop = 0;                               // fall through to safe path
    }

    prep_kernel<<<680, 256, 0, stream>>>(xoff, xabs, h0, W_soc, W_emb, b_emb,
                                         W_ih, W_hh, W_out, ws);
    pgemm_kernel<<<dim3(64, 32), 256, 0, stream>>>(ws);
    pool_kernel<<<1024, 256, 0, stream>>>(b_soc, W_ih, ws);
    gates_kernel<<<dim3(64, 8), 256, 0, stream>>>(c0, b_ih, b_hh, W_ih, ws);
    pwout_kernel<<<512, 256, 0, stream>>>(b_out, W_ih, ws, out);
}

// Round 6
// 117.994 us; speedup vs baseline: 1.0035x; 1.0028x over previous
//
#include <hip/hip_runtime.h>
#include <hip/hip_bf16.h>

#define NN_ 1024

// ws layout (~15 MB of 256 MiB ws)
#define U_WGF  0         // ushort idx: 131072  Wg fragment-major, quadrant-remapped:
                         //   ((jt*8+kb)*4+q)*128 + jl*8 + r ; jorig = (jt&3)*128+(jt>>2)*16+jl
#define U_ACTH 655360    // ushort: 262144 act_hi[n][k] 1024x256 (0-63 emb, 64-127 pool, 128-255 h0)
#define U_P    917504    // ushort: 4194304 P[m][g*64+e] bf16 (8 MB)
#define F_WOUT 2555904   // float idx: 16384 f32 WoutT[r][j] 128x128, j>=120 zero
#define I_OFF  2703360   // uint idx: 1048576 per-agent neighbor offsets (1024 each)
#define I_CNT  3751936   // uint idx: 1024 per-agent neighbor counts

typedef __attribute__((ext_vector_type(8))) short short8;
typedef __attribute__((ext_vector_type(4))) float floatx4;

__device__ __forceinline__ float b2f_(unsigned short u) {
    return __uint_as_float(((unsigned)u) << 16);           // bf16 -> f32, exact
}
__device__ __forceinline__ unsigned short f2bu(float f) {  // f32 -> bf16 bits (RNE)
    __hip_bfloat16 b = __float2bfloat16(f);
    return *(unsigned short*)&b;
}
__device__ __forceinline__ float ldin(const void* p, int i, int isbf) {
    return isbf ? b2f_(((const unsigned short*)p)[i]) : ((const float*)p)[i];
}
__device__ __forceinline__ int detect_bf16(const void* Wih, int tid) {
    unsigned wv = ((const unsigned*)Wih)[tid];
    unsigned e8 = (wv >> 7) & 0xFFu;
    return (__syncthreads_count((e8 >= 96u && e8 <= 134u) ? 1 : 0) > 128) ? 1 : 0;
}
// load 8 consecutive input elements starting at element idx as bf16x8
__device__ __forceinline__ short8 ld8_bf(const void* p, int idx, int isbf) {
    if (isbf) return *(const short8*)((const unsigned short*)p + idx);
    const float4* f = (const float4*)((const float*)p + idx);
    float4 a = f[0], b = f[1];
    short8 r;
    r[0] = (short)f2bu(a.x); r[1] = (short)f2bu(a.y);
    r[2] = (short)f2bu(a.z); r[3] = (short)f2bu(a.w);
    r[4] = (short)f2bu(b.x); r[5] = (short)f2bu(b.y);
    r[6] = (short)f2bu(b.z); r[7] = (short)f2bu(b.w);
    return r;
}

// ---- K1 (936 blocks): direct-load P-GEMM (512) + detect (256) + staging (168) ----
// blocks [0,512):   pgemm, M_b=32 x N_b=256, h0/Wsoc loaded directly (R1-proven)
// blocks [512,768): neighbor detect, 4 agents each
// blocks [768,832): Wg fragment remap   [832,840): WoutT
// blocks [840,872): emb -> ACTH k=0..63 [872,936): h0 -> ACTH k=128..255
__global__ __launch_bounds__(256) void fused1_kernel(
        const void* __restrict__ xoff, const void* __restrict__ xabs,
        const void* __restrict__ h0,   const void* __restrict__ Wsoc,
        const void* __restrict__ Wemb, const void* __restrict__ bemb,
        const void* __restrict__ Wih,  const void* __restrict__ Whh,
        const void* __restrict__ Wout, float* __restrict__ ws) {
    const int tid = threadIdx.x;
    const int bid = blockIdx.x;
    const int isbf = detect_bf16(Wih, tid);
    unsigned short* u = (unsigned short*)ws;

    if (bid < 512) {
        // P[m][col] = sum_k h0[m][k] * Wsoc[e][g*128+k],  col = g*64+e
        unsigned short* P16 = u + U_P;
        const int mg = bid >> 4, ng = bid & 15;
        const int lane = tid & 63, wv = tid >> 6;
        const int m = lane & 15, q = lane >> 4;
        short8 ah[2][4];
#pragma unroll
        for (int mt = 0; mt < 2; ++mt) {
            const int row = mg * 32 + mt * 16 + m;
#pragma unroll
            for (int kb = 0; kb < 4; ++kb)
                ah[mt][kb] = ld8_bf(h0, row * 128 + kb * 32 + q * 8, isbf);
        }
#pragma unroll
        for (int c = 0; c < 4; ++c) {
            const int ct = wv * 4 + c;
            const int col = ng * 256 + ct * 16 + m;
            const int g = col >> 6, e = col & 63;
            short8 bf[4];
#pragma unroll
            for (int kb = 0; kb < 4; ++kb)
                bf[kb] = ld8_bf(Wsoc, e * 8192 + g * 128 + kb * 32 + q * 8, isbf);
            floatx4 c0_ = {0.f, 0.f, 0.f, 0.f}, c1_ = {0.f, 0.f, 0.f, 0.f};
#pragma unroll
            for (int kb = 0; kb < 4; ++kb) {
                c0_ = __builtin_amdgcn_mfma_f32_16x16x32_bf16(ah[0][kb], bf[kb], c0_, 0, 0, 0);
                c1_ = __builtin_amdgcn_mfma_f32_16x16x32_bf16(ah[1][kb], bf[kb], c1_, 0, 0, 0);
            }
#pragma unroll
            for (int r = 0; r < 4; ++r) {          // D: col=lane&15, row=q*4+r
                P16[(mg * 32 + q * 4 + r) * 4096 + col]      = f2bu(c0_[r]);
                P16[(mg * 32 + 16 + q * 4 + r) * 4096 + col] = f2bu(c1_[r]);
            }
        }
    } else if (bid < 768) {
        // neighbor detection, 4 agents/block -> OFF lists + CNT
        __shared__ float xs_[2048];
        __shared__ int cnt_s[4];
        for (int i = tid; i < 2048; i += 256) xs_[i] = ldin(xabs, i, isbf);
        if (tid < 4) cnt_s[tid] = 0;
        __syncthreads();
        const int a = tid >> 6, t = tid & 63;
        const int n = (bid - 512) * 4 + a;
        unsigned* OFF = (unsigned*)ws + I_OFF + n * 1024;
        const float xsn = xs_[2 * n]     - 0.2f;   // x[n] - NS/2
        const float ysn = xs_[2 * n + 1] - 0.2f;
        for (int i = t; i < NN_; i += 64) {
            float dx = xs_[2 * i]     - xsn;
            float dy = xs_[2 * i + 1] - ysn;
            int cx = (int)floorf(dx / 0.4f * 8.0f);
            int cy = (int)floorf(dy / 0.4f * 8.0f);
            bool valid = (dx >= 0.0f) && (dx < 0.4f) && (dy >= 0.0f) && (dy < 0.4f)
                      && (cx >= 0) && (cx < 8) && (cy >= 0) && (cy < 8) && (i != n);
            if (valid) {
                int pos = atomicAdd(&cnt_s[a], 1);
                OFF[pos] = (unsigned)(i * 4096 + ((cy * 8 + cx) << 6));
            }
        }
        __syncthreads();
        if (tid < 4) ((unsigned*)ws)[I_CNT + (bid - 512) * 4 + tid] = (unsigned)cnt_s[tid];
    } else if (bid < 832) {                        // Wg fragment-major, quadrant-remapped
        const int t0 = (bid - 768) * 2048 + tid * 8;
        const int jl = (t0 >> 3) & 15, q = (t0 >> 7) & 3, kb = (t0 >> 9) & 7, jt = t0 >> 12;
        const int j = (jt & 3) * 128 + (jt >> 2) * 16 + jl;
        const int k0 = kb * 32 + q * 8;
        unsigned short hv[8];
#pragma unroll
        for (int r = 0; r < 8; r++) {
            int k = k0 + r;
            float v = (k < 128) ? ldin(Wih, j * 128 + k, isbf)
                                : ldin(Whh, j * 128 + (k - 128), isbf);
            hv[r] = f2bu(v);
        }
        *(short8*)(u + U_WGF + t0) = *(short8*)hv;
    } else if (bid < 840) {                        // WoutT f32 [r][j]
        const int t2 = (bid - 832) * 2048 + tid * 8;
        const int r = t2 >> 7, j0 = t2 & 127;
#pragma unroll
        for (int i = 0; i < 8; i++) {
            int j = j0 + i;
            ws[F_WOUT + t2 + i] = (j < 120) ? ldin(Wout, j * 128 + r, isbf) : 0.0f;
        }
    } else if (bid < 872) {                        // emb -> act k=0..63
        const int t2 = (bid - 840) * 2048 + tid * 8;
        const int n = t2 >> 6, e0 = t2 & 63;
        const float x0 = ldin(xoff, 2 * n, isbf), x1 = ldin(xoff, 2 * n + 1, isbf);
        unsigned short hv[8];
#pragma unroll
        for (int i = 0; i < 8; i++) {
            int e = e0 + i;
            float v = fmaf(x0, ldin(Wemb, 2 * e, isbf),
                      fmaf(x1, ldin(Wemb, 2 * e + 1, isbf), ldin(bemb, e, isbf)));
            hv[i] = f2bu(fmaxf(v, 0.0f));
        }
        *(short8*)(u + U_ACTH + n * 256 + e0) = *(short8*)hv;
    } else {                                       // h0 -> act k=128..255
        const int t2 = (bid - 872) * 2048 + tid * 8;
        const int n = t2 >> 7, k = t2 & 127;
        unsigned short hv[8];
#pragma unroll
        for (int i = 0; i < 8; i++) hv[i] = f2bu(ldin(h0, t2 + i, isbf));
        *(short8*)(u + U_ACTH + n * 256 + 128 + k) = *(short8*)hv;
    }
}

// ---- K2: pool gather, 1 agent/block (1024 blocks) — verbatim round 3 ----
__global__ __launch_bounds__(256) void pool_kernel(const void* __restrict__ b_soc,
                                                   const void* __restrict__ Wih_det,
                                                   float* __restrict__ ws) {
    __shared__ int off_s[1024];
    __shared__ float4 red4[16][16];
    const int tid = threadIdx.x;
    const int isbf = detect_bf16(Wih_det, tid);
    const int n = blockIdx.x;
    unsigned short* u = (unsigned short*)ws;
    const int cc = (int)((const unsigned*)ws)[I_CNT + n];
    {
        const unsigned* lst = (const unsigned*)ws + I_OFF + n * 1024;
        for (int j = tid; j < cc; j += 256) off_s[j] = (int)lst[j];
    }
    __syncthreads();
    {   // branch-free gathers: 16 streams x 16 e4-lanes
        const unsigned short* P16 = (const unsigned short*)ws + U_P;
        const int strm = tid >> 4, e4 = tid & 15;
        float ax = 0.0f, ay = 0.0f, az = 0.0f, aw = 0.0f;
        for (int j = strm; j < cc; j += 16) {
            int o = off_s[j];
            ushort4 uu = *(const ushort4*)(P16 + o + 4 * e4);
            ax += b2f_(uu.x); ay += b2f_(uu.y); az += b2f_(uu.z); aw += b2f_(uu.w);
        }
        red4[strm][e4] = make_float4(ax, ay, az, aw);
    }
    __syncthreads();
    if (tid < 16) {
        float s[4] = {0.0f, 0.0f, 0.0f, 0.0f};
#pragma unroll
        for (int s16 = 0; s16 < 16; s16++) {
            float4 r = red4[s16][tid];
            s[0] += r.x; s[1] += r.y; s[2] += r.z; s[3] += r.w;
        }
        int e = 4 * tid;
#pragma unroll
        for (int i = 0; i < 4; i++) {
            float v = fmaxf(s[i] + ldin(b_soc, e + i, isbf), 0.0f);
            u[U_ACTH + n * 256 + 64 + e + i] = f2bu(v);
        }
    }
}

// ---- K3: gates MFMA + LSTM pointwise + fused pwout partials (atomicAdd) ----
// grid (64,8): block = 16 agents x r-range [16y,16y+16), all 4 quadrants.
// Each block adds its r-segment's contribution to out; out pre-zeroed by memset.
__global__ __launch_bounds__(256) void gates_kernel(const void* __restrict__ c0,
                                                    const void* __restrict__ b_ih,
                                                    const void* __restrict__ b_hh,
                                                    const void* __restrict__ b_out,
                                                    const void* __restrict__ Wih_det,
                                                    const float* __restrict__ ws,
                                                    float* __restrict__ out) {
    __shared__ float gl[16][68];                   // [agent][quad*16 + jl]
    __shared__ float hnl[16][16];                  // [agent][rl]
    const int tid = threadIdx.x;
    const int isbf = detect_bf16(Wih_det, tid);
    const unsigned short* u = (const unsigned short*)ws;
    const short* Ah = (const short*)(u + U_ACTH);
    const short* Wg = (const short*)(u + U_WGF);
    const int lane = tid & 63, wv = tid >> 6, m = lane & 15, q = lane >> 4;
    const int m0 = blockIdx.x * 16, y = blockIdx.y;
    const int jt = y * 4 + wv;                     // fragment-major tile id
    floatx4 acc = {0.0f, 0.0f, 0.0f, 0.0f};
#pragma unroll
    for (int kb = 0; kb < 8; kb++) {
        short8 ah = *(const short8*)(Ah + (m0 + m) * 256 + kb * 32 + q * 8);
        short8 b  = *(const short8*)(Wg + (jt * 8 + kb) * 512 + q * 128 + m * 8);
        acc = __builtin_amdgcn_mfma_f32_16x16x32_bf16(ah, b, acc, 0, 0, 0);
    }
    const int jorig = wv * 128 + y * 16 + m;       // quadrant wv, row y*16+m
    const float bias = ldin(b_ih, jorig, isbf) + ldin(b_hh, jorig, isbf);
#pragma unroll
    for (int r = 0; r < 4; r++)                    // D row = q*4+r = agent local
        gl[q * 4 + r][wv * 16 + m] = acc[r] + bias;
    __syncthreads();
    {   // LSTM pointwise for this block's 16 agents x 16 r -> hnl
        const int a = tid >> 4, rl = tid & 15;
        const int n = m0 + a, rg = y * 16 + rl;
        float iv = gl[a][rl],      fv = gl[a][16 + rl];
        float gv = gl[a][32 + rl], ov = gl[a][48 + rl];
        float si = 1.0f / (1.0f + expf(-iv));
        float sf = 1.0f / (1.0f + expf(-fv));
        float so = 1.0f / (1.0f + expf(-ov));
        float cc = sf * ldin(c0, n * 128 + rg, isbf) + si * tanhf(gv);
        hnl[a][rl] = so * tanhf(cc);
    }
    __syncthreads();
    {   // pwout partial: this block's 16-r segment, 16 agents x 120 j
        const int a = tid >> 4, jb = tid & 15;
        const int n = m0 + a;
        const float* WT = ws + F_WOUT + (y * 16) * 128;   // rows 16y..16y+15
        for (int j = jb; j < 120; j += 16) {
            float acc2 = (y == 0) ? ldin(b_out, j, isbf) : 0.0f;
#pragma unroll
            for (int rl = 0; rl < 16; ++rl)
                acc2 = fmaf(hnl[a][rl], WT[rl * 128 + j], acc2);
            int ch = j / 20, wc = j - ch * 20;
            atomicAdd(&out[ch * 20480 + n * 20 + wc], acc2);   // f32 [6][1024][20]
        }
    }
}

extern "C" void kernel_launch(void* const* d_in, const int* in_sizes, int n_in,
                              void* d_out, int out_size, void* d_ws, size_t ws_size,
                              hipStream_t stream) {
    const void* xoff  = d_in[0];
    const void* xabs  = d_in[1];
    const void* h0    = d_in[2];
    const void* c0    = d_in[3];
    const void* W_emb = d_in[4];
    const void* b_emb = d_in[5];
    const void* W_soc = d_in[6];
    const void* b_soc = d_in[7];
    const void* W_ih  = d_in[8];
    const void* W_hh  = d_in[9];
    const void* b_ih  = d_in[10];
    const void* b_hh  = d_in[11];
    const void* W_out = d_in[12];
    const void* b_out = d_in[13];
    float* ws = (float*)d_ws;
    float* out = (float*)d_out;

    hipMemsetAsync(d_out, 0, (size_t)out_size, stream);   // out accumulated via atomics
    fused1_kernel<<<936, 256, 0, stream>>>(xoff, xabs, h0, W_soc, W_emb, b_emb,
                                           W_ih, W_hh, W_out, ws);
    pool_kernel<<<1024, 256, 0, stream>>>(b_soc, W_ih, ws);
    gates_kernel<<<dim3(64, 8), 256, 0, stream>>>(c0, b_ih, b_hh, b_out,
                                                  W_ih, ws, out);
}